// Round 13
// baseline (183.211 us; speedup 1.0000x reference)
//
#include <hip/hip_runtime.h>
#include <stdint.h>

// QNetSNN: B=16384, HIDDEN=64, T=40.  R17: R16 + mm_a hoist (dep-break).
// R16: 129.5us, VALU 56 / Mfma 20 / stall ~24, occupancy 20 (4 chains/SIMD),
// clean (WRITE 64KB). Remaining stall is source-order serialization: mm_a's
// B operand ([enc_a|z_s], bAC ix 0..4) is ready at barrier A, but the z_a
// ds_write (ix 5..8) sits between thresh_a and mm_a's ds_read in program
// order and the compiler can't prove LDS non-aliasing -> each step eats an
// extra serial LDS latency + MFMA drain. Fix: load ALL B fragments right
// after barrier A and issue mm_s + mm_a as one 32-MFMA block before
// combine_S/thresh_a/stage-z_a (reads precede writes; slots disjoint).
// Pure reorder of independent ops -> absmax exactly 0.01171875.
// Risk bought: accS+accA live together (+32 reg peak). Failure reads:
// occupancy ~12 or WRITE in MBs => budget blown => hoist loads only.
//
// LDS (32768 B): init quant scratch [4][64][128]; steady:
//   [0,2048) bS g0 | [2048,4096) bS g1 | [4096,12288) bAC g0 2par |
//   [12288,20480) bAC g1 2par | [20480,21504) part 2par x 2grp x 64 f32.
// Swizzle: physical = row*STRIDE + (((ix&8)|((ix&7)^(row&7)))<<4) + intra,
//   ix = logical_byte>>4 (identical R10-R16).
// WS k: 0..47 Wsin | 48..111 Wsrec | pad0.  WA k: 0..7 Wain | 16..79 Warec | pad0.
// WC k: 0..63 Wcin1 (z_s) | 64..127 Wcin2+Wcrec fold (z_a); B base col 16.
// bufS cols: 0..47 enc | 48..111 z_c.  bufAC cols: 0..7 enc_a | 16..79 z_s
//   | 80..143 z_a.  Wave h: z_s ix=1+h, z_a ix=5+h, z_c ix=3+h, enc ix=h.

typedef int   i32x4 __attribute__((ext_vector_type(4)));
typedef float f32x4 __attribute__((ext_vector_type(4)));

__launch_bounds__(256)
__attribute__((amdgpu_waves_per_eu(2, 2)))
__global__ void snn_main(const float* __restrict__ state, const float* __restrict__ action,
                         const float* __restrict__ Wsin, const float* __restrict__ Wsrec,
                         const float* __restrict__ Wain, const float* __restrict__ Warec,
                         const float* __restrict__ Wcin, const float* __restrict__ Wcrec,
                         const float* __restrict__ Wro, float* __restrict__ out) {
    __shared__ __align__(16) char smem[32768];

    const int tid  = threadIdx.x;
    const int lane = tid & 63, h = tid >> 6;    // wave h owns neurons h*16..h*16+15
    const int l15  = lane & 15, g = lane >> 4;
    const int s    = l15 & 7;                   // swizzle key (row = l15)

    // ---- quantize one weight into 4 signed-7-bit digits (all steps exact) ----
    auto quant = [](float w, int* d) {
        float x = w * 0x1p25f;                                   // exact (pow2)
        int d3 = __float2int_rn(x * 0x1p-21f); x -= (float)d3 * 0x1p21f;
        int d2 = __float2int_rn(x * 0x1p-14f); x -= (float)d2 * 0x1p14f;
        int d1 = __float2int_rn(x * 0x1p-7f);  x -= (float)d1 * 0x1p7f;
        int d0 = __float2int_rn(x);                              // residual <= 2^-27
        d[0] = d0; d[1] = d1; d[2] = d2; d[3] = d3;
    };
    auto quantMat = [&](auto src) {   // 64x128 -> smem[0,32768) 4 planes, swizzled rows
        for (int i4 = tid; i4 < 2048; i4 += 256) {
            int base = i4 * 4; int n = base >> 7, k0 = base & 127;
            int sw = n * 128 + ((((k0 >> 4) ^ (n & 7)) << 4) | (k0 & 15));
            uint32_t pk[4] = {0u, 0u, 0u, 0u};
            #pragma unroll
            for (int e = 0; e < 4; ++e) {
                int d[4]; quant(src(n, k0 + e), d);
                #pragma unroll
                for (int p = 0; p < 4; ++p) pk[p] |= (uint32_t)(uint8_t)(char)d[p] << (8 * e);
            }
            #pragma unroll
            for (int p = 0; p < 4; ++p) *(uint32_t*)(smem + p * 8192 + sw) = pk[p];
        }
    };

    // swizzled 16B-slot offsets for B-fragment reads
    const int cS0 = ((g ^ s) << 4);             // ix = g        (kt=0)
    const int cS1 = (((4 + g) ^ s) << 4);       // ix = 4+g      (kt=1)
    const int i1c = 5 + g;
    const int cC0 = (((1 + g) ^ s) << 4);                        // layer-c kt=0
    const int cC1 = (((i1c & 8) | ((i1c & 7) ^ s)) << 4);        // layer-c kt=1

    i32x4 AS[4][2], AA[4][2], AC[4][2];   // [plane][kt], this wave's 16 neurons (shared by both groups)
    const int arow = (h * 16 + l15) * 128;

    quantMat([&](int n, int k) -> float {
        if (k < 48)  return Wsin[n * 48 + k];
        if (k < 112) return Wsrec[n * 64 + (k - 48)];
        return 0.f;
    });
    __syncthreads();
    #pragma unroll
    for (int p = 0; p < 4; ++p)
    #pragma unroll
    for (int kt = 0; kt < 2; ++kt)
        AS[p][kt] = *(const i32x4*)(smem + p * 8192 + arow + (kt ? cS1 : cS0));
    __syncthreads();

    quantMat([&](int n, int k) -> float {
        float w = Wcin[n * 128 + k];
        if (k >= 64) w += Wcrec[n * 64 + (k - 64)];   // fold (matches R6, absmax 0.0)
        return w;
    });
    __syncthreads();
    #pragma unroll
    for (int p = 0; p < 4; ++p)
    #pragma unroll
    for (int kt = 0; kt < 2; ++kt)
        AC[p][kt] = *(const i32x4*)(smem + p * 8192 + arow + (kt ? cS1 : cS0));
    __syncthreads();

    quantMat([&](int n, int k) -> float {
        if (k < 8)              return Wain[n * 8 + k];
        if (k >= 16 && k < 80)  return Warec[n * 64 + (k - 16)];
        return 0.f;
    });
    __syncthreads();
    #pragma unroll
    for (int p = 0; p < 4; ++p)
    #pragma unroll
    for (int kt = 0; kt < 2; ++kt)
        AA[p][kt] = *(const i32x4*)(smem + p * 8192 + arow + (kt ? cS1 : cS0));
    __syncthreads();   // scratch free; staging may now overwrite

    char*  bS_[2]  = { smem,        smem + 2048 };          // [16][128] swizzled
    char*  bACb[2] = { smem + 4096, smem + 12288 };         // 2par x [16][256] swizzled
    float* part0   = (float*)(smem + 20480);                // 2par x [2grp][64]

    // staging offsets (wave h) -- same within each group's buffers
    const int ixZs = 1 + h, ixZa = 5 + h, ixZc = 3 + h;
    const int zsOff = l15 * 256 + (((ixZs & 8) | ((ixZs & 7) ^ s)) << 4) + 4 * g;
    const int zaOff = l15 * 256 + (((ixZa & 8) | ((ixZa & 7) ^ s)) << 4) + 4 * g;
    const int zcOff = l15 * 128 + ((ixZc ^ s) << 4) + 4 * g;
    const int encOffS = l15 * 128 + ((h ^ s) << 4) + 4 * g;   // waves 0..2 -> bufS
    const int encOffA = l15 * 256 + (s << 4) + 4 * g;         // wave 3 (g<2) -> bufAC

    const int rowBase = blockIdx.x * 32;
    const i32x4 zeroI = (i32x4){0, 0, 0, 0};

    // encoder currents: wave h covers features f = h*16 + 4g + e, group gr row +16*gr
    float cur[2][4], venc[2][4];
    #pragma unroll
    for (int gr = 0; gr < 2; ++gr)
    #pragma unroll
    for (int e = 0; e < 4; ++e) {
        int f = h * 16 + 4 * g + e;
        int row = rowBase + gr * 16 + l15;
        float c = 0.f;
        if (f < 24)      c = fmaxf( 50.f * state[row * 24 + f], 0.f);
        else if (f < 48) c = fmaxf(-50.f * state[row * 24 + f - 24], 0.f);
        else if (f < 52) c = fmaxf( 50.f * action[row * 4 + f - 48], 0.f);
        else if (f < 56) c = fmaxf(-50.f * action[row * 4 + f - 52], 0.f);
        cur[gr][e] = c; venc[gr][e] = 0.f;
    }

    float wrof[4];   // D-layout: n = h*16 + 4g + r
    #pragma unroll
    for (int r = 0; r < 4; ++r) wrof[r] = Wro[h * 16 + 4 * g + r];

    f32x4 v4[2], ic4[2];
    bool zc[2][4];
    float vli[2], ili[2], vmax[2];
    #pragma unroll
    for (int gr = 0; gr < 2; ++gr) {
        v4[gr] = (f32x4){0.f,0.f,0.f,0.f}; ic4[gr] = (f32x4){0.f,0.f,0.f,0.f};
        vli[gr] = 0.f; ili[gr] = 0.f; vmax[gr] = 0.f;
        #pragma unroll
        for (int r = 0; r < 4; ++r) zc[gr][r] = false;
    }

    for (int t = 0; t < 40; ++t) {
        char* bAC[2] = { bACb[0] + ((t & 1) << 12), bACb[1] + ((t & 1) << 12) };
        float* part  = part0 + ((t & 1) << 7);   // [2grp][64]

        f32x4 vs[2], va[2], icS[2], icA[2];
        bool zs[2][4], za[2][4];

        // ---- stage z_c (prev step; zeros at t=0) + layer-s threshold + z_s + enc ----
        #pragma unroll
        for (int gr = 0; gr < 2; ++gr) {
            uint32_t zw = (zc[gr][0]?1u:0u)|(zc[gr][1]?0x100u:0u)|(zc[gr][2]?0x10000u:0u)|(zc[gr][3]?0x1000000u:0u);
            *(uint32_t*)(bS_[gr] + zcOff) = zw;

            f32x4 vd = v4[gr] + 0.1f * (ic4[gr] - v4[gr]);
            #pragma unroll
            for (int r = 0; r < 4; ++r) { zs[gr][r] = (vd[r] - 1.0f) > 0.f; if (zs[gr][r]) vd[r] = 0.f; }
            vs[gr] = vd;
            uint32_t zw2 = (zs[gr][0]?1u:0u)|(zs[gr][1]?0x100u:0u)|(zs[gr][2]?0x10000u:0u)|(zs[gr][3]?0x1000000u:0u);
            *(uint32_t*)(bAC[gr] + zsOff) = zw2;

            uint32_t wrd = 0;
            #pragma unroll
            for (int e = 0; e < 4; ++e) {
                float vn = venc[gr][e] + 0.1f * (cur[gr][e] - venc[gr][e]);
                bool sp = (vn - 1.0f) > 0.f;
                venc[gr][e] = sp ? 0.f : vn;
                wrd |= sp ? (1u << (8 * e)) : 0u;
            }
            if (h < 3)          *(uint32_t*)(bS_[gr] + encOffS) = wrd;
            else if (g < 2)     *(uint32_t*)(bAC[gr] + encOffA) = wrd;
        }

        __syncthreads();   // A: enc + z_s + z_c visible (both groups)

        // ---- hoisted B-fragment loads: mm_s AND mm_a operands (all ready at A;
        //      mm_a's slots ix 0..4 are disjoint from the z_a writes ix 5..8) ----
        i32x4 bs0[2], bs1[2], ba0[2], ba1[2];
        #pragma unroll
        for (int gr = 0; gr < 2; ++gr) {
            bs0[gr] = *(const i32x4*)(bS_[gr] + l15 * 128 + cS0);
            bs1[gr] = *(const i32x4*)(bS_[gr] + l15 * 128 + cS1);
            ba0[gr] = *(const i32x4*)(bAC[gr] + l15 * 256 + cS0);
            ba1[gr] = *(const i32x4*)(bAC[gr] + l15 * 256 + cS1);
        }

        // ---- mm_s + mm_a as one MFMA block (mutually independent) ----
        i32x4 accS[2][4], accA[2][4];
        #pragma unroll
        for (int gr = 0; gr < 2; ++gr)
        #pragma unroll
        for (int p = 0; p < 4; ++p) {
            accS[gr][p] = __builtin_amdgcn_mfma_i32_16x16x64_i8(AS[p][0], bs0[gr], zeroI, 0, 0, 0);
            accS[gr][p] = __builtin_amdgcn_mfma_i32_16x16x64_i8(AS[p][1], bs1[gr], accS[gr][p], 0, 0, 0);
        }
        #pragma unroll
        for (int gr = 0; gr < 2; ++gr)
        #pragma unroll
        for (int p = 0; p < 4; ++p) {
            accA[gr][p] = __builtin_amdgcn_mfma_i32_16x16x64_i8(AA[p][0], ba0[gr], zeroI, 0, 0, 0);
            accA[gr][p] = __builtin_amdgcn_mfma_i32_16x16x64_i8(AA[p][1], ba1[gr], accA[gr][p], 0, 0, 0);
        }

        // ---- combine S -> icS ----
        #pragma unroll
        for (int gr = 0; gr < 2; ++gr) {
            i32x4 hi = accS[gr][3] * 128 + accS[gr][2];
            i32x4 lo = accS[gr][1] * 128 + accS[gr][0];
            f32x4 idec = ic4[gr] - 0.2f * ic4[gr];
            #pragma unroll
            for (int r = 0; r < 4; ++r)
                icS[gr][r] = fmaf((float)lo[r], 0x1p-25f, fmaf((float)hi[r], 0x1p-11f, idec[r]));
        }

        // ---- layer-a threshold + stage z_a (both groups) ----
        #pragma unroll
        for (int gr = 0; gr < 2; ++gr) {
            f32x4 vd = vs[gr] + 0.1f * (icS[gr] - vs[gr]);
            #pragma unroll
            for (int r = 0; r < 4; ++r) { za[gr][r] = (vd[r] - 1.0f) > 0.f; if (za[gr][r]) vd[r] = 0.f; }
            va[gr] = vd;
            uint32_t zw = (za[gr][0]?1u:0u)|(za[gr][1]?0x100u:0u)|(za[gr][2]?0x10000u:0u)|(za[gr][3]?0x1000000u:0u);
            *(uint32_t*)(bAC[gr] + zaOff) = zw;
        }

        // ---- combine A -> icA (accA already computed; decay seed from icS) ----
        #pragma unroll
        for (int gr = 0; gr < 2; ++gr) {
            i32x4 hi = accA[gr][3] * 128 + accA[gr][2];
            i32x4 lo = accA[gr][1] * 128 + accA[gr][0];
            f32x4 idec = icS[gr] - 0.2f * icS[gr];
            #pragma unroll
            for (int r = 0; r < 4; ++r)
                icA[gr][r] = fmaf((float)lo[r], 0x1p-25f, fmaf((float)hi[r], 0x1p-11f, idec[r]));
        }

        // ---- layer-c threshold + readout partials (both groups) ----
        #pragma unroll
        for (int gr = 0; gr < 2; ++gr) {
            f32x4 vd = va[gr] + 0.1f * (icA[gr] - va[gr]);
            #pragma unroll
            for (int r = 0; r < 4; ++r) { zc[gr][r] = (vd[r] - 1.0f) > 0.f; if (zc[gr][r]) vd[r] = 0.f; }
            v4[gr] = vd;

            float pr = 0.f;
            #pragma unroll
            for (int r = 0; r < 4; ++r) pr += zc[gr][r] ? wrof[r] : 0.f;
            pr += __shfl_xor(pr, 16);
            pr += __shfl_xor(pr, 32);
            if (g == 0) part[gr * 64 + h * 16 + l15] = pr;
        }

        __syncthreads();   // C: z_a + partials visible (both groups)

        // ---- layer-c matmul ([z_s|z_a] @ WC^T, B logical base col 16) + LI ----
        #pragma unroll
        for (int gr = 0; gr < 2; ++gr) {
            i32x4 b0 = *(const i32x4*)(bAC[gr] + l15 * 256 + cC0);
            i32x4 b1 = *(const i32x4*)(bAC[gr] + l15 * 256 + cC1);
            i32x4 acc[4];
            #pragma unroll
            for (int p = 0; p < 4; ++p) {
                acc[p] = __builtin_amdgcn_mfma_i32_16x16x64_i8(AC[p][0], b0, zeroI, 0, 0, 0);
                acc[p] = __builtin_amdgcn_mfma_i32_16x16x64_i8(AC[p][1], b1, acc[p], 0, 0, 0);
            }
            i32x4 hi = acc[3] * 128 + acc[2];
            i32x4 lo = acc[1] * 128 + acc[0];
            f32x4 idec = icA[gr] - 0.2f * icA[gr];
            #pragma unroll
            for (int r = 0; r < 4; ++r)
                ic4[gr][r] = fmaf((float)lo[r], 0x1p-25f, fmaf((float)hi[r], 0x1p-11f, idec[r]));

            // ---- LI readout ----
            float pt = part[gr * 64 + l15] + part[gr * 64 + 16 + l15]
                     + part[gr * 64 + 32 + l15] + part[gr * 64 + 48 + l15];
            float vnew = vli[gr] + 0.1f * (ili[gr] - vli[gr]);
            ili[gr] = (ili[gr] - 0.2f * ili[gr]) + pt;
            vli[gr] = vnew;
            vmax[gr] = fmaxf(vmax[gr], vli[gr]);
        }
        // no end barrier: parity buffers + barrier C cover cross-step hazards
    }

    if (h == 0 && g == 0) {
        out[rowBase + l15]      = vmax[0];
        out[rowBase + 16 + l15] = vmax[1];
    }
}

extern "C" void kernel_launch(void* const* d_in, const int* in_sizes, int n_in,
                              void* d_out, int out_size, void* d_ws, size_t ws_size,
                              hipStream_t stream) {
    const float* state  = (const float*)d_in[0];
    const float* action = (const float*)d_in[1];
    const float* Wsin   = (const float*)d_in[2];
    const float* Wsrec  = (const float*)d_in[3];
    const float* Wain   = (const float*)d_in[4];
    const float* Warec  = (const float*)d_in[5];
    const float* Wcin   = (const float*)d_in[6];
    const float* Wcrec  = (const float*)d_in[7];
    const float* Wro    = (const float*)d_in[8];
    float* out = (float*)d_out;

    const int B = in_sizes[0] / 24;  // 16384
    snn_main<<<B / 32, 256, 0, stream>>>(state, action, Wsin, Wsrec, Wain, Warec,
                                         Wcin, Wcrec, Wro, out);
}

// Round 14
// 180.898 us; speedup vs baseline: 1.0128x; 1.0128x over previous
//
#include <hip/hip_runtime.h>
#include <stdint.h>

// QNetSNN: B=16384, HIDDEN=64, T=40.  R18: R16 + t-loop unroll-by-2.
// R17 (mm_a hoist) was neutral-negative (132 vs 129.5) -> intra-step
// reordering exhausted; reverted to R16 body. Remaining seam: the loop
// back-edge. [barrier C -> mm_c+LI] (MFMA-drain, VALU-idle) and the next
// iteration's [stage z_c / thresh_s / encoder] (pure VALU, independent of
// mm_c except thresh_s's ic4 dep) are in different iterations -> compiler
// can't interleave. #pragma unroll 2 exposes the pair to the scheduler and
// makes parity (t&1) compile-time per copy (kills parity addressing VALU).
// Arithmetic unchanged -> absmax exactly 0.01171875. Failure reads:
// occupancy ~12 / VGPR >>160 => unroll blew regs => R16 final; dur flat =>
// structure at practical ceiling, declare with R16.
//
// LDS (32768 B): init quant scratch [4][64][128]; steady:
//   [0,2048) bS g0 | [2048,4096) bS g1 | [4096,12288) bAC g0 2par |
//   [12288,20480) bAC g1 2par | [20480,21504) part 2par x 2grp x 64 f32.
// Swizzle: physical = row*STRIDE + (((ix&8)|((ix&7)^(row&7)))<<4) + intra,
//   ix = logical_byte>>4 (identical R10-R17).
// WS k: 0..47 Wsin | 48..111 Wsrec | pad0.  WA k: 0..7 Wain | 16..79 Warec | pad0.
// WC k: 0..63 Wcin1 (z_s) | 64..127 Wcin2+Wcrec fold (z_a); B base col 16.
// bufS cols: 0..47 enc | 48..111 z_c.  bufAC cols: 0..7 enc_a | 16..79 z_s
//   | 80..143 z_a.  Wave h: z_s ix=1+h, z_a ix=5+h, z_c ix=3+h, enc ix=h.

typedef int   i32x4 __attribute__((ext_vector_type(4)));
typedef float f32x4 __attribute__((ext_vector_type(4)));

__launch_bounds__(256)
__attribute__((amdgpu_waves_per_eu(2, 2)))
__global__ void snn_main(const float* __restrict__ state, const float* __restrict__ action,
                         const float* __restrict__ Wsin, const float* __restrict__ Wsrec,
                         const float* __restrict__ Wain, const float* __restrict__ Warec,
                         const float* __restrict__ Wcin, const float* __restrict__ Wcrec,
                         const float* __restrict__ Wro, float* __restrict__ out) {
    __shared__ __align__(16) char smem[32768];

    const int tid  = threadIdx.x;
    const int lane = tid & 63, h = tid >> 6;    // wave h owns neurons h*16..h*16+15
    const int l15  = lane & 15, g = lane >> 4;
    const int s    = l15 & 7;                   // swizzle key (row = l15)

    // ---- quantize one weight into 4 signed-7-bit digits (all steps exact) ----
    auto quant = [](float w, int* d) {
        float x = w * 0x1p25f;                                   // exact (pow2)
        int d3 = __float2int_rn(x * 0x1p-21f); x -= (float)d3 * 0x1p21f;
        int d2 = __float2int_rn(x * 0x1p-14f); x -= (float)d2 * 0x1p14f;
        int d1 = __float2int_rn(x * 0x1p-7f);  x -= (float)d1 * 0x1p7f;
        int d0 = __float2int_rn(x);                              // residual <= 2^-27
        d[0] = d0; d[1] = d1; d[2] = d2; d[3] = d3;
    };
    auto quantMat = [&](auto src) {   // 64x128 -> smem[0,32768) 4 planes, swizzled rows
        for (int i4 = tid; i4 < 2048; i4 += 256) {
            int base = i4 * 4; int n = base >> 7, k0 = base & 127;
            int sw = n * 128 + ((((k0 >> 4) ^ (n & 7)) << 4) | (k0 & 15));
            uint32_t pk[4] = {0u, 0u, 0u, 0u};
            #pragma unroll
            for (int e = 0; e < 4; ++e) {
                int d[4]; quant(src(n, k0 + e), d);
                #pragma unroll
                for (int p = 0; p < 4; ++p) pk[p] |= (uint32_t)(uint8_t)(char)d[p] << (8 * e);
            }
            #pragma unroll
            for (int p = 0; p < 4; ++p) *(uint32_t*)(smem + p * 8192 + sw) = pk[p];
        }
    };

    // swizzled 16B-slot offsets for B-fragment reads
    const int cS0 = ((g ^ s) << 4);             // ix = g        (kt=0)
    const int cS1 = (((4 + g) ^ s) << 4);       // ix = 4+g      (kt=1)
    const int i1c = 5 + g;
    const int cC0 = (((1 + g) ^ s) << 4);                        // layer-c kt=0
    const int cC1 = (((i1c & 8) | ((i1c & 7) ^ s)) << 4);        // layer-c kt=1

    i32x4 AS[4][2], AA[4][2], AC[4][2];   // [plane][kt], this wave's 16 neurons (shared by both groups)
    const int arow = (h * 16 + l15) * 128;

    quantMat([&](int n, int k) -> float {
        if (k < 48)  return Wsin[n * 48 + k];
        if (k < 112) return Wsrec[n * 64 + (k - 48)];
        return 0.f;
    });
    __syncthreads();
    #pragma unroll
    for (int p = 0; p < 4; ++p)
    #pragma unroll
    for (int kt = 0; kt < 2; ++kt)
        AS[p][kt] = *(const i32x4*)(smem + p * 8192 + arow + (kt ? cS1 : cS0));
    __syncthreads();

    quantMat([&](int n, int k) -> float {
        float w = Wcin[n * 128 + k];
        if (k >= 64) w += Wcrec[n * 64 + (k - 64)];   // fold (matches R6, absmax 0.0)
        return w;
    });
    __syncthreads();
    #pragma unroll
    for (int p = 0; p < 4; ++p)
    #pragma unroll
    for (int kt = 0; kt < 2; ++kt)
        AC[p][kt] = *(const i32x4*)(smem + p * 8192 + arow + (kt ? cS1 : cS0));
    __syncthreads();

    quantMat([&](int n, int k) -> float {
        if (k < 8)              return Wain[n * 8 + k];
        if (k >= 16 && k < 80)  return Warec[n * 64 + (k - 16)];
        return 0.f;
    });
    __syncthreads();
    #pragma unroll
    for (int p = 0; p < 4; ++p)
    #pragma unroll
    for (int kt = 0; kt < 2; ++kt)
        AA[p][kt] = *(const i32x4*)(smem + p * 8192 + arow + (kt ? cS1 : cS0));
    __syncthreads();   // scratch free; staging may now overwrite

    char*  bS_[2]  = { smem,        smem + 2048 };          // [16][128] swizzled
    char*  bACb[2] = { smem + 4096, smem + 12288 };         // 2par x [16][256] swizzled
    float* part0   = (float*)(smem + 20480);                // 2par x [2grp][64]

    // staging offsets (wave h) -- same within each group's buffers
    const int ixZs = 1 + h, ixZa = 5 + h, ixZc = 3 + h;
    const int zsOff = l15 * 256 + (((ixZs & 8) | ((ixZs & 7) ^ s)) << 4) + 4 * g;
    const int zaOff = l15 * 256 + (((ixZa & 8) | ((ixZa & 7) ^ s)) << 4) + 4 * g;
    const int zcOff = l15 * 128 + ((ixZc ^ s) << 4) + 4 * g;
    const int encOffS = l15 * 128 + ((h ^ s) << 4) + 4 * g;   // waves 0..2 -> bufS
    const int encOffA = l15 * 256 + (s << 4) + 4 * g;         // wave 3 (g<2) -> bufAC

    const int rowBase = blockIdx.x * 32;
    const i32x4 zeroI = (i32x4){0, 0, 0, 0};

    // encoder currents: wave h covers features f = h*16 + 4g + e, group gr row +16*gr
    float cur[2][4], venc[2][4];
    #pragma unroll
    for (int gr = 0; gr < 2; ++gr)
    #pragma unroll
    for (int e = 0; e < 4; ++e) {
        int f = h * 16 + 4 * g + e;
        int row = rowBase + gr * 16 + l15;
        float c = 0.f;
        if (f < 24)      c = fmaxf( 50.f * state[row * 24 + f], 0.f);
        else if (f < 48) c = fmaxf(-50.f * state[row * 24 + f - 24], 0.f);
        else if (f < 52) c = fmaxf( 50.f * action[row * 4 + f - 48], 0.f);
        else if (f < 56) c = fmaxf(-50.f * action[row * 4 + f - 52], 0.f);
        cur[gr][e] = c; venc[gr][e] = 0.f;
    }

    float wrof[4];   // D-layout: n = h*16 + 4g + r
    #pragma unroll
    for (int r = 0; r < 4; ++r) wrof[r] = Wro[h * 16 + 4 * g + r];

    f32x4 v4[2], ic4[2];
    bool zc[2][4];
    float vli[2], ili[2], vmax[2];
    #pragma unroll
    for (int gr = 0; gr < 2; ++gr) {
        v4[gr] = (f32x4){0.f,0.f,0.f,0.f}; ic4[gr] = (f32x4){0.f,0.f,0.f,0.f};
        vli[gr] = 0.f; ili[gr] = 0.f; vmax[gr] = 0.f;
        #pragma unroll
        for (int r = 0; r < 4; ++r) zc[gr][r] = false;
    }

    #pragma unroll 2
    for (int t = 0; t < 40; ++t) {
        char* bAC[2] = { bACb[0] + ((t & 1) << 12), bACb[1] + ((t & 1) << 12) };
        float* part  = part0 + ((t & 1) << 7);   // [2grp][64]

        f32x4 vs[2], va[2], icS[2], icA[2];
        bool zs[2][4], za[2][4];

        // ---- stage z_c (prev step; zeros at t=0) + layer-s threshold + z_s + enc ----
        #pragma unroll
        for (int gr = 0; gr < 2; ++gr) {
            uint32_t zw = (zc[gr][0]?1u:0u)|(zc[gr][1]?0x100u:0u)|(zc[gr][2]?0x10000u:0u)|(zc[gr][3]?0x1000000u:0u);
            *(uint32_t*)(bS_[gr] + zcOff) = zw;

            f32x4 vd = v4[gr] + 0.1f * (ic4[gr] - v4[gr]);
            #pragma unroll
            for (int r = 0; r < 4; ++r) { zs[gr][r] = (vd[r] - 1.0f) > 0.f; if (zs[gr][r]) vd[r] = 0.f; }
            vs[gr] = vd;
            uint32_t zw2 = (zs[gr][0]?1u:0u)|(zs[gr][1]?0x100u:0u)|(zs[gr][2]?0x10000u:0u)|(zs[gr][3]?0x1000000u:0u);
            *(uint32_t*)(bAC[gr] + zsOff) = zw2;

            uint32_t wrd = 0;
            #pragma unroll
            for (int e = 0; e < 4; ++e) {
                float vn = venc[gr][e] + 0.1f * (cur[gr][e] - venc[gr][e]);
                bool sp = (vn - 1.0f) > 0.f;
                venc[gr][e] = sp ? 0.f : vn;
                wrd |= sp ? (1u << (8 * e)) : 0u;
            }
            if (h < 3)          *(uint32_t*)(bS_[gr] + encOffS) = wrd;
            else if (g < 2)     *(uint32_t*)(bAC[gr] + encOffA) = wrd;
        }

        __syncthreads();   // A: enc + z_s + z_c visible (both groups)

        // ---- layer-s matmul (zero-C seeded, groups interleaved) ----
        #pragma unroll
        for (int gr = 0; gr < 2; ++gr) {
            i32x4 b0 = *(const i32x4*)(bS_[gr] + l15 * 128 + cS0);
            i32x4 b1 = *(const i32x4*)(bS_[gr] + l15 * 128 + cS1);
            i32x4 acc[4];
            #pragma unroll
            for (int p = 0; p < 4; ++p) {
                acc[p] = __builtin_amdgcn_mfma_i32_16x16x64_i8(AS[p][0], b0, zeroI, 0, 0, 0);
                acc[p] = __builtin_amdgcn_mfma_i32_16x16x64_i8(AS[p][1], b1, acc[p], 0, 0, 0);
            }
            i32x4 hi = acc[3] * 128 + acc[2];
            i32x4 lo = acc[1] * 128 + acc[0];
            f32x4 idec = ic4[gr] - 0.2f * ic4[gr];
            #pragma unroll
            for (int r = 0; r < 4; ++r)
                icS[gr][r] = fmaf((float)lo[r], 0x1p-25f, fmaf((float)hi[r], 0x1p-11f, idec[r]));
        }

        // ---- layer-a threshold + stage z_a (both groups) ----
        #pragma unroll
        for (int gr = 0; gr < 2; ++gr) {
            f32x4 vd = vs[gr] + 0.1f * (icS[gr] - vs[gr]);
            #pragma unroll
            for (int r = 0; r < 4; ++r) { za[gr][r] = (vd[r] - 1.0f) > 0.f; if (za[gr][r]) vd[r] = 0.f; }
            va[gr] = vd;
            uint32_t zw = (za[gr][0]?1u:0u)|(za[gr][1]?0x100u:0u)|(za[gr][2]?0x10000u:0u)|(za[gr][3]?0x1000000u:0u);
            *(uint32_t*)(bAC[gr] + zaOff) = zw;
        }

        // ---- layer-a matmul (B cols 80..127 race-exposed x zero WA digits -> exact) ----
        #pragma unroll
        for (int gr = 0; gr < 2; ++gr) {
            i32x4 b0 = *(const i32x4*)(bAC[gr] + l15 * 256 + cS0);
            i32x4 b1 = *(const i32x4*)(bAC[gr] + l15 * 256 + cS1);
            i32x4 acc[4];
            #pragma unroll
            for (int p = 0; p < 4; ++p) {
                acc[p] = __builtin_amdgcn_mfma_i32_16x16x64_i8(AA[p][0], b0, zeroI, 0, 0, 0);
                acc[p] = __builtin_amdgcn_mfma_i32_16x16x64_i8(AA[p][1], b1, acc[p], 0, 0, 0);
            }
            i32x4 hi = acc[3] * 128 + acc[2];
            i32x4 lo = acc[1] * 128 + acc[0];
            f32x4 idec = icS[gr] - 0.2f * icS[gr];
            #pragma unroll
            for (int r = 0; r < 4; ++r)
                icA[gr][r] = fmaf((float)lo[r], 0x1p-25f, fmaf((float)hi[r], 0x1p-11f, idec[r]));
        }

        // ---- layer-c threshold + readout partials (both groups) ----
        #pragma unroll
        for (int gr = 0; gr < 2; ++gr) {
            f32x4 vd = va[gr] + 0.1f * (icA[gr] - va[gr]);
            #pragma unroll
            for (int r = 0; r < 4; ++r) { zc[gr][r] = (vd[r] - 1.0f) > 0.f; if (zc[gr][r]) vd[r] = 0.f; }
            v4[gr] = vd;

            float pr = 0.f;
            #pragma unroll
            for (int r = 0; r < 4; ++r) pr += zc[gr][r] ? wrof[r] : 0.f;
            pr += __shfl_xor(pr, 16);
            pr += __shfl_xor(pr, 32);
            if (g == 0) part[gr * 64 + h * 16 + l15] = pr;
        }

        __syncthreads();   // C: z_a + partials visible (both groups)

        // ---- layer-c matmul ([z_s|z_a] @ WC^T, B logical base col 16) + LI ----
        #pragma unroll
        for (int gr = 0; gr < 2; ++gr) {
            i32x4 b0 = *(const i32x4*)(bAC[gr] + l15 * 256 + cC0);
            i32x4 b1 = *(const i32x4*)(bAC[gr] + l15 * 256 + cC1);
            i32x4 acc[4];
            #pragma unroll
            for (int p = 0; p < 4; ++p) {
                acc[p] = __builtin_amdgcn_mfma_i32_16x16x64_i8(AC[p][0], b0, zeroI, 0, 0, 0);
                acc[p] = __builtin_amdgcn_mfma_i32_16x16x64_i8(AC[p][1], b1, acc[p], 0, 0, 0);
            }
            i32x4 hi = acc[3] * 128 + acc[2];
            i32x4 lo = acc[1] * 128 + acc[0];
            f32x4 idec = icA[gr] - 0.2f * icA[gr];
            #pragma unroll
            for (int r = 0; r < 4; ++r)
                ic4[gr][r] = fmaf((float)lo[r], 0x1p-25f, fmaf((float)hi[r], 0x1p-11f, idec[r]));

            // ---- LI readout ----
            float pt = part[gr * 64 + l15] + part[gr * 64 + 16 + l15]
                     + part[gr * 64 + 32 + l15] + part[gr * 64 + 48 + l15];
            float vnew = vli[gr] + 0.1f * (ili[gr] - vli[gr]);
            ili[gr] = (ili[gr] - 0.2f * ili[gr]) + pt;
            vli[gr] = vnew;
            vmax[gr] = fmaxf(vmax[gr], vli[gr]);
        }
        // no end barrier: parity buffers + barrier C cover cross-step hazards
    }

    if (h == 0 && g == 0) {
        out[rowBase + l15]      = vmax[0];
        out[rowBase + 16 + l15] = vmax[1];
    }
}

extern "C" void kernel_launch(void* const* d_in, const int* in_sizes, int n_in,
                              void* d_out, int out_size, void* d_ws, size_t ws_size,
                              hipStream_t stream) {
    const float* state  = (const float*)d_in[0];
    const float* action = (const float*)d_in[1];
    const float* Wsin   = (const float*)d_in[2];
    const float* Wsrec  = (const float*)d_in[3];
    const float* Wain   = (const float*)d_in[4];
    const float* Warec  = (const float*)d_in[5];
    const float* Wcin   = (const float*)d_in[6];
    const float* Wcrec  = (const float*)d_in[7];
    const float* Wro    = (const float*)d_in[8];
    float* out = (float*)d_out;

    const int B = in_sizes[0] / 24;  // 16384
    snn_main<<<B / 32, 256, 0, stream>>>(state, action, Wsin, Wsrec, Wain, Warec,
                                         Wcin, Wcrec, Wro, out);
}